// Round 3
// baseline (234.780 us; speedup 1.0000x reference)
//
#include <hip/hip_runtime.h>

// Problem constants: B=8, N=2048, D=128.
#define BSZ   8
#define NN    2048
#define DD    128
#define NROWS (BSZ * NN)          // 16384
#define N4    (NN / 4)            // 512 float4 per output row
#define P_A   0.8f
#define P_B   0.2f
#define LOG2E 1.44269504088896f

typedef float f4v __attribute__((ext_vector_type(4)));  // native clang vector (nontemporal-compatible)

// Kernel 1: per-row dot products. One 64-lane wave per row, float2 loads.
// si[row] = dot(x[row], W[0:128]) + bias ; sj[row] = dot(x[row], W[128:256])
__global__ __launch_bounds__(256) void row_dots(const float* __restrict__ x,
                                                const float* __restrict__ W,
                                                const float* __restrict__ bias,
                                                float* __restrict__ si,
                                                float* __restrict__ sj) {
    int gtid = blockIdx.x * blockDim.x + threadIdx.x;
    int row  = gtid >> 6;         // wave index = row (grid sized exactly)
    int lane = threadIdx.x & 63;

    const float2* xr = (const float2*)(x + (size_t)row * DD);
    const float2* W2 = (const float2*)W;
    float2 xv = xr[lane];          // elements 2*lane, 2*lane+1
    float2 wi = W2[lane];
    float2 wj = W2[lane + 64];

    float a = fmaf(xv.x, wi.x, xv.y * wi.y);
    float c = fmaf(xv.x, wj.x, xv.y * wj.y);

    #pragma unroll
    for (int off = 32; off > 0; off >>= 1) {
        a += __shfl_down(a, off, 64);
        c += __shfl_down(c, off, 64);
    }
    if (lane == 0) {
        si[row] = a + bias[0];
        sj[row] = c;
    }
}

__device__ __forceinline__ float fast_sigmoid(float t) {
    // sigmoid(t) = 1 / (1 + 2^(-t*log2(e)))   -> v_exp_f32 + v_rcp_f32
    float e = __builtin_amdgcn_exp2f(-t * LOG2E);
    return __builtin_amdgcn_rcpf(1.0f + e);
}

// Kernel 2: one block per output row (b,i). 256 threads x 2 float4 = 2048 floats.
__global__ __launch_bounds__(256) void fuse_kernel(const f4v* __restrict__ adj,
                                                   const float* __restrict__ si,
                                                   const f4v* __restrict__ sj,
                                                   f4v* __restrict__ out) {
    const int row = blockIdx.x;            // b*N + i, 0..16383
    const int tid = threadIdx.x;
    const int b   = row >> 11;             // N = 2048

    const float s = si[row];               // block-uniform -> scalar load
    const f4v* __restrict__ sjr = sj + (b << 9);
    const size_t base = (size_t)row * N4;

    #pragma unroll
    for (int k = 0; k < 2; ++k) {
        const int j4 = tid + k * 256;
        f4v sv = sjr[j4];                                      // L2-resident (8 KB/row)
        f4v av = __builtin_nontemporal_load(&adj[base + j4]);  // stream once
        f4v o;
        o.x = fmaf(P_A, fast_sigmoid(s + sv.x), P_B * av.x);
        o.y = fmaf(P_A, fast_sigmoid(s + sv.y), P_B * av.y);
        o.z = fmaf(P_A, fast_sigmoid(s + sv.z), P_B * av.z);
        o.w = fmaf(P_A, fast_sigmoid(s + sv.w), P_B * av.w);
        __builtin_nontemporal_store(o, &out[base + j4]);
    }
}

extern "C" void kernel_launch(void* const* d_in, const int* in_sizes, int n_in,
                              void* d_out, int out_size, void* d_ws, size_t ws_size,
                              hipStream_t stream) {
    const float* x    = (const float*)d_in[0];   // [B,N,D]
    const float* adj  = (const float*)d_in[1];   // [B,N,N]
    const float* W    = (const float*)d_in[2];   // [2D]
    const float* bias = (const float*)d_in[3];   // scalar

    float* si = (float*)d_ws;            // NROWS floats
    float* sj = si + NROWS;              // NROWS floats (128 KiB total)

    row_dots<<<NROWS * 64 / 256, 256, 0, stream>>>(x, W, bias, si, sj);

    fuse_kernel<<<NROWS, 256, 0, stream>>>(
        (const f4v*)adj, si, (const f4v*)sj, (f4v*)d_out);
}